// Round 13
// baseline (537.799 us; speedup 1.0000x reference)
//
#include <hip/hip_runtime.h>

#define N_NODES 50000
#define N_EDGES 1600000
#define DIM 64
#define NBK 196          // buckets of 256 dst-nodes
#define BIN_BLOCKS 391   // ceil(1.6M / 4096)
#define CSR_CAP 12288    // per-bucket slots
#define QCAP 3072        // per-quarter slots (mult-16-padded mean ~2560, ~8-sigma margin)
#define GEMM_BLOCKS 197  // covers 50000 rows + dummy zero row
#define NB_AGG 12500     // aggregate blocks (4 nodes/block)

// f32 -> bf16 round-to-nearest-even
__device__ __forceinline__ unsigned short f2bf(float f) {
    union { float f; unsigned u; } v; v.f = f;
    unsigned r = v.u + 0x7FFF + ((v.u >> 16) & 1);
    return (unsigned short)(r >> 16);
}
__device__ __forceinline__ float bf_lo(unsigned u) {
    union { unsigned u; float f; } v; v.u = u << 16;  return v.f;
}
__device__ __forceinline__ float bf_hi(unsigned u) {
    union { unsigned u; float f; } v; v.u = u & 0xFFFF0000u;  return v.f;
}
__device__ __forceinline__ float bf2f(unsigned short h) {
    union { unsigned u; float f; } v; v.u = ((unsigned)h) << 16;  return v.f;
}

// Fused: blocks [0, BIN_BLOCKS) bin edges + per-node degree histogram
// (bcur/ncnt zero-based, memset first); blocks [BIN_BLOCKS, ..) T = feat@W1^T.
// LDS: binning arrays UNION gemm's Ws (disjoint paths) -> 27 KB (was 40.4).
__global__ __launch_bounds__(256, 4) void bin_and_gemm1(const int* __restrict__ src,
                                                        const int* __restrict__ dst,
                                                        int* __restrict__ bcur,
                                                        int* __restrict__ ncnt,
                                                        int* __restrict__ binned,
                                                        const float* __restrict__ X,
                                                        const float* __restrict__ W,
                                                        unsigned short* __restrict__ T) {
    __shared__ __align__(16) char smem[27008];
    int tid = threadIdx.x;

    if (blockIdx.x >= BIN_BLOCKS) {
        // ---------------- GEMM path (feat f32 -> T bf16) ----------------
        float* Ws = (float*)smem;  // 16 KB
#pragma unroll
        for (int j = 0; j < 16; ++j) Ws[j * 256 + tid] = W[j * 256 + tid];
        __syncthreads();

        int n = (blockIdx.x - BIN_BLOCKS) * 256 + tid;
        if (n > N_NODES) return;
        ushort4* tp = (ushort4*)(T + (size_t)n * 64);
        if (n == N_NODES) {  // dummy zero row (pad target)
            ushort4 z = {0, 0, 0, 0};
#pragma unroll
            for (int k = 0; k < 16; ++k) tp[k] = z;
            return;
        }

        // x packed as 32 bf16-pairs (saves 32 VGPRs vs f32x64)
        unsigned xq[32];
        const float4* xp = (const float4*)(X + (size_t)n * 64);
#pragma unroll
        for (int k = 0; k < 16; ++k) {
            float4 xv = xp[k];
            xq[2 * k]     = ((unsigned)f2bf(xv.y) << 16) | f2bf(xv.x);
            xq[2 * k + 1] = ((unsigned)f2bf(xv.w) << 16) | f2bf(xv.z);
        }

        for (int fg = 0; fg < 16; ++fg) {
            float r[4];
#pragma unroll
            for (int fi = 0; fi < 4; ++fi) {
                int f = fg * 4 + fi;
                float acc = 0.f;
#pragma unroll
                for (int k4 = 0; k4 < 16; ++k4) {
                    float4 w = *(const float4*)&Ws[f * 64 + k4 * 4];
                    unsigned p0 = xq[2 * k4], p1 = xq[2 * k4 + 1];
                    acc += bf_lo(p0) * w.x + bf_hi(p0) * w.y +
                           bf_lo(p1) * w.z + bf_hi(p1) * w.w;
                }
                r[fi] = acc;
            }
            ushort4 o;
            o.x = f2bf(r[0]); o.y = f2bf(r[1]); o.z = f2bf(r[2]); o.w = f2bf(r[3]);
            tp[fg] = o;
        }
        return;
    }

    // ---------------- Binning path (R6-proven + degree histogram) ----------------
    int* cnt    = (int*)smem;        // 196
    int* lofs   = cnt + NBK;         // 196
    int* shiftv = lofs + NBK;        // 196
    int* sb     = shiftv + NBK;      // 256
    int* stag   = sb + 256;          // 4096 ints (offset 6736 B <- 16-aligned)
    unsigned char* stb = (unsigned char*)(stag + 4096);  // 4096 B

    if (tid < NBK) cnt[tid] = 0;
    __syncthreads();

    int base = blockIdx.x * 4096;
    int nedge = N_EDGES - base;
    if (nedge > 4096) nedge = 4096;

    int myb[16], myr[16], myp[16];
#pragma unroll
    for (int i = 0; i < 16; ++i) {
        int e = base + i * 256 + tid;
        myb[i] = -1;
        if (e < N_EDGES) {
            int s = src[e], d = dst[e];
            int b = d >> 8;
            myb[i] = b;
            myp[i] = ((d & 255) << 16) | s;
            myr[i] = atomicAdd(&cnt[b], 1);
            atomicAdd(&ncnt[d], 1);   // per-node degree (global, 50K lines)
        }
    }
    __syncthreads();

    int c = (tid < NBK) ? cnt[tid] : 0;
    sb[tid] = c;
    __syncthreads();
    for (int off = 1; off < 256; off <<= 1) {
        int u = (tid >= off) ? sb[tid - off] : 0;
        __syncthreads();
        sb[tid] += u;
        __syncthreads();
    }
    if (tid < NBK) {
        lofs[tid] = sb[tid] - c;
        if (c) shiftv[tid] = tid * CSR_CAP + atomicAdd(&bcur[tid * 16], c) - lofs[tid];
    }
    __syncthreads();

#pragma unroll
    for (int i = 0; i < 16; ++i) {
        if (myb[i] >= 0) {
            int idx = lofs[myb[i]] + myr[i];
            stag[idx] = myp[i];
            stb[idx] = (unsigned char)myb[i];
        }
    }
    __syncthreads();

    for (int i = tid; i < nedge; i += 256)
        binned[i + shiftv[stb[i]]] = stag[i];
}

// One workgroup per (bucket, dst-quarter). Degrees precomputed in ncnt ->
// SINGLE pass over binned (place only) + per-node pad-tail fill.
// Counts padded to mult-16 with dummy src = N_NODES. nodeinfo=(pcnt<<23)|pos.
__global__ __launch_bounds__(256) void build_csr(const int* __restrict__ binned,
                                                 const int* __restrict__ bcur,
                                                 const int* __restrict__ ncnt,
                                                 unsigned* __restrict__ nodeinfo,
                                                 unsigned short* __restrict__ csr16) {
    __shared__ int cnt[64], cnt2[64], ofs[64], sb[64];
    int tid = threadIdx.x;
    int b = blockIdx.x >> 2;
    int q = blockIdx.x & 3;
    int ibase = b * CSR_CAP;
    int qbase = (b * 4 + q) * QCAP;
    int m = bcur[b * 16];          // bucket edge count
    if (m > CSR_CAP) m = CSR_CAP;
    int node = (b << 8) + (q << 6) + tid;

    int v = 0, c0 = 0;
    if (tid < 64) {
        c0 = (node < N_NODES) ? ncnt[node] : 0;
        cnt[tid] = c0;
        cnt2[tid] = 0;
        v = (c0 + 15) & ~15;       // mult-16 pad
        sb[tid] = v;
    }
    __syncthreads();
    for (int off = 1; off < 64; off <<= 1) {
        int u = (tid >= off && tid < 64) ? sb[tid - off] : 0;
        __syncthreads();
        if (tid < 64) sb[tid] += u;
        __syncthreads();
    }
    if (tid < 64) {
        ofs[tid] = sb[tid] - v;
        if (node < N_NODES)
            nodeinfo[node] = ((unsigned)v << 23) | (unsigned)(qbase + ofs[tid]);
        // pad tail fill: [c0, v) gets dummy row index
        int o = qbase + ofs[tid];
        for (int i = c0; i < v; ++i) csr16[o + i] = (unsigned short)N_NODES;
    }
    __syncthreads();

    // place pass (only pass over binned)
    for (int i = tid; i < m; i += 256) {
        int p = binned[ibase + i];
        int dl = (p >> 16) & 255;
        if ((dl >> 6) == q) {
            int r = atomicAdd(&cnt2[dl & 63], 1);
            csr16[qbase + ofs[dl & 63] + r] = (unsigned short)(p & 0xFFFF);
        }
    }
}

// T(bf16) = X(bf16) @ W^T; dummy row zeroed. (layer 2)
__global__ __launch_bounds__(256) void gemm64_bf16(const unsigned short* __restrict__ X,
                                                   const float* __restrict__ W,
                                                   unsigned short* __restrict__ T,
                                                   int n_rows) {
    __shared__ float Ws[64 * 64];
    int tid = threadIdx.x;
#pragma unroll
    for (int j = 0; j < 16; ++j) Ws[j * 256 + tid] = W[j * 256 + tid];
    __syncthreads();

    int n = blockIdx.x * 256 + tid;
    if (n >= n_rows) {
        if (n == n_rows) {
            ushort4 z = {0, 0, 0, 0};
            ushort4* tp = (ushort4*)(T + (size_t)n * 64);
#pragma unroll
            for (int k = 0; k < 16; ++k) tp[k] = z;
        }
        return;
    }

    uint4 xr[8];  // 64 bf16 = 128 B
    const uint4* xp = (const uint4*)(X + (size_t)n * 64);
#pragma unroll
    for (int k = 0; k < 8; ++k) xr[k] = xp[k];
    const unsigned* xq = (const unsigned*)xr;

    ushort4* tp = (ushort4*)(T + (size_t)n * 64);
    for (int fg = 0; fg < 16; ++fg) {
        float r[4];
#pragma unroll
        for (int fi = 0; fi < 4; ++fi) {
            int f = fg * 4 + fi;
            float acc = 0.f;
#pragma unroll
            for (int k4 = 0; k4 < 16; ++k4) {
                float4 w = *(const float4*)&Ws[f * 64 + k4 * 4];
                unsigned p0 = xq[2 * k4], p1 = xq[2 * k4 + 1];
                acc += bf_lo(p0) * w.x + bf_hi(p0) * w.y +
                       bf_lo(p1) * w.z + bf_hi(p1) * w.w;
            }
            r[fi] = acc;
        }
        ushort4 o;
        o.x = f2bf(r[0]); o.y = f2bf(r[1]); o.z = f2bf(r[2]); o.w = f2bf(r[3]);
        tp[fg] = o;
    }
}

// R11-proven aggregate: one 64-lane wave per node, lane = feature.
// Counts mult-16: 2 index uint4 loads + 16 independent 128B row gathers/iter.
__global__ __launch_bounds__(256) void aggregate(const unsigned short* __restrict__ T,
                                                 const unsigned short* __restrict__ csr,
                                                 const unsigned* __restrict__ nodeinfo,
                                                 const float* __restrict__ bias,
                                                 void* __restrict__ outp,
                                                 int mode) {
    int node = blockIdx.x * 4 + (threadIdx.x >> 6);
    int lane = threadIdx.x & 63;
    if (node >= N_NODES) return;
    unsigned info = nodeinfo[node];
    int pos = (int)(info & 0x7FFFFFu);
    int groups = (int)(info >> 23) >> 3;   // even (pcnt mult 16)
    const uint4* ix = (const uint4*)(csr + pos);  // 32B-aligned
    float acc = bias[lane];
    float acc2 = 0.f;
    for (int g = 0; g < groups; g += 2) {
        uint4 ia = ix[g];
        uint4 ib = ix[g + 1];
        int s0 = ia.x & 0xFFFF, s1 = ia.x >> 16;
        int s2 = ia.y & 0xFFFF, s3 = ia.y >> 16;
        int s4 = ia.z & 0xFFFF, s5 = ia.z >> 16;
        int s6 = ia.w & 0xFFFF, s7 = ia.w >> 16;
        int u0 = ib.x & 0xFFFF, u1 = ib.x >> 16;
        int u2 = ib.y & 0xFFFF, u3 = ib.y >> 16;
        int u4 = ib.z & 0xFFFF, u5 = ib.z >> 16;
        int u6 = ib.w & 0xFFFF, u7 = ib.w >> 16;
        unsigned short v0 = T[(size_t)s0 * DIM + lane];
        unsigned short v1 = T[(size_t)s1 * DIM + lane];
        unsigned short v2 = T[(size_t)s2 * DIM + lane];
        unsigned short v3 = T[(size_t)s3 * DIM + lane];
        unsigned short v4 = T[(size_t)s4 * DIM + lane];
        unsigned short v5 = T[(size_t)s5 * DIM + lane];
        unsigned short v6 = T[(size_t)s6 * DIM + lane];
        unsigned short v7 = T[(size_t)s7 * DIM + lane];
        unsigned short w0 = T[(size_t)u0 * DIM + lane];
        unsigned short w1 = T[(size_t)u1 * DIM + lane];
        unsigned short w2 = T[(size_t)u2 * DIM + lane];
        unsigned short w3 = T[(size_t)u3 * DIM + lane];
        unsigned short w4 = T[(size_t)u4 * DIM + lane];
        unsigned short w5 = T[(size_t)u5 * DIM + lane];
        unsigned short w6 = T[(size_t)u6 * DIM + lane];
        unsigned short w7 = T[(size_t)u7 * DIM + lane];
        acc  += (bf2f(v0) + bf2f(v1)) + (bf2f(v2) + bf2f(v3)) +
                (bf2f(v4) + bf2f(v5)) + (bf2f(v6) + bf2f(v7));
        acc2 += (bf2f(w0) + bf2f(w1)) + (bf2f(w2) + bf2f(w3)) +
                (bf2f(w4) + bf2f(w5)) + (bf2f(w6) + bf2f(w7));
    }
    acc += acc2;
    if (mode) {
        float e = __expf(2.f * acc);
        acc = 1.f - 2.f / (e + 1.f);
        ((unsigned short*)outp)[(size_t)node * DIM + lane] = f2bf(acc);
    } else {
        ((float*)outp)[(size_t)node * DIM + lane] = acc;
    }
}

extern "C" void kernel_launch(void* const* d_in, const int* in_sizes, int n_in,
                              void* d_out, int out_size, void* d_ws, size_t ws_size,
                              hipStream_t stream) {
    const float* feat = (const float*)d_in[0];
    const int*   src  = (const int*)d_in[1];
    const int*   dst  = (const int*)d_in[2];
    const float* W1   = (const float*)d_in[3];
    const float* b1   = (const float*)d_in[4];
    const float* W2   = (const float*)d_in[5];
    const float* b2   = (const float*)d_in[6];

    // ws layout (~21.5 MB)
    int*            binned   = (int*)d_ws;                                // 196*12288 ints
    unsigned short* csr16    = (unsigned short*)(binned + NBK * CSR_CAP); // 784*3072 ushort
    unsigned*       nodeinfo = (unsigned*)(csr16 + NBK * 4 * QCAP);       // 50000
    int*            bcur     = (int*)(nodeinfo + N_NODES);                // 196*16
    int*            ncnt     = bcur + NBK * 16;                           // 50000
    unsigned short* t        = (unsigned short*)(ncnt + N_NODES);         // 50001*64 bf16

    unsigned short* h = (unsigned short*)d_out;  // bf16 h staged in d_out
    float* out = (float*)d_out;

    // ---- CSR build + layer-1 transform (overlapped) ----
    hipMemsetAsync(bcur, 0, (NBK * 16 + N_NODES) * sizeof(int), stream);
    bin_and_gemm1<<<BIN_BLOCKS + GEMM_BLOCKS, 256, 0, stream>>>(
        src, dst, bcur, ncnt, binned, feat, W1, t);
    build_csr<<<NBK * 4, 256, 0, stream>>>(binned, bcur, ncnt, nodeinfo, csr16);

    // ---- Layer 1 aggregate: h = tanh(agg + b1), bf16 -> d_out ----
    aggregate<<<NB_AGG, 256, 0, stream>>>(t, csr16, nodeinfo, b1, h, 1);

    // ---- Layer 2: out = agg(h @ W2^T) + b2, f32 ----
    gemm64_bf16<<<GEMM_BLOCKS, 256, 0, stream>>>(h, W2, t, N_NODES);
    aggregate<<<NB_AGG, 256, 0, stream>>>(t, csr16, nodeinfo, b2, out, 0);
}

// Round 14
// 282.851 us; speedup vs baseline: 1.9013x; 1.9013x over previous
//
#include <hip/hip_runtime.h>

#define N_NODES 50000
#define N_EDGES 1600000
#define DIM 64
#define NBK 196          // buckets of 256 dst-nodes
#define BIN_BLOCKS 391   // ceil(1.6M / 4096)
#define CSR_CAP 12288    // per-bucket slots
#define QCAP 3072        // per-quarter slots (mult-16-padded mean ~2560, ~8-sigma margin)
#define GEMM_BLOCKS 197  // covers 50000 rows + dummy zero row
#define NB_AGG 12500     // aggregate blocks (4 nodes/block)

// f32 -> bf16 round-to-nearest-even
__device__ __forceinline__ unsigned short f2bf(float f) {
    union { float f; unsigned u; } v; v.f = f;
    unsigned r = v.u + 0x7FFF + ((v.u >> 16) & 1);
    return (unsigned short)(r >> 16);
}
__device__ __forceinline__ float bf_lo(unsigned u) {
    union { unsigned u; float f; } v; v.u = u << 16;  return v.f;
}
__device__ __forceinline__ float bf_hi(unsigned u) {
    union { unsigned u; float f; } v; v.u = u & 0xFFFF0000u;  return v.f;
}
__device__ __forceinline__ float bf2f(unsigned short h) {
    union { unsigned u; float f; } v; v.u = ((unsigned)h) << 16;  return v.f;
}

// Fused (R11-exact config; NO min-waves clause — 256,4 forced 64 VGPR and
// spilled the binning arrays to scratch: 358us, R13): blocks [0,BIN_BLOCKS)
// bin edges + per-node degree histogram; blocks [BIN_BLOCKS,..) T = feat@W1^T.
__global__ __launch_bounds__(256) void bin_and_gemm1(const int* __restrict__ src,
                                                     const int* __restrict__ dst,
                                                     int* __restrict__ bcur,
                                                     int* __restrict__ ncnt,
                                                     int* __restrict__ binned,
                                                     const float* __restrict__ X,
                                                     const float* __restrict__ W,
                                                     unsigned short* __restrict__ T) {
    __shared__ int cnt[NBK];
    __shared__ int lofs[NBK];
    __shared__ int shiftv[NBK];
    __shared__ int sb[256];
    __shared__ int stag[4096];
    __shared__ unsigned char stb[4096];
    __shared__ float Ws[64 * 64];
    int tid = threadIdx.x;

    if (blockIdx.x >= BIN_BLOCKS) {
        // ---------------- GEMM path (feat f32 -> T bf16) ----------------
#pragma unroll
        for (int j = 0; j < 16; ++j) Ws[j * 256 + tid] = W[j * 256 + tid];
        __syncthreads();

        int n = (blockIdx.x - BIN_BLOCKS) * 256 + tid;
        if (n > N_NODES) return;
        ushort4* tp = (ushort4*)(T + (size_t)n * 64);
        if (n == N_NODES) {  // dummy zero row (pad target)
            ushort4 z = {0, 0, 0, 0};
#pragma unroll
            for (int k = 0; k < 16; ++k) tp[k] = z;
            return;
        }

        float4 x[16];
        const float4* xp = (const float4*)(X + (size_t)n * 64);
#pragma unroll
        for (int k = 0; k < 16; ++k) x[k] = xp[k];

        for (int fg = 0; fg < 16; ++fg) {
            float r[4];
#pragma unroll
            for (int fi = 0; fi < 4; ++fi) {
                int f = fg * 4 + fi;
                float acc = 0.f;
#pragma unroll
                for (int k4 = 0; k4 < 16; ++k4) {
                    float4 w = *(const float4*)&Ws[f * 64 + k4 * 4];
                    float4 xv = x[k4];
                    acc += xv.x * w.x + xv.y * w.y + xv.z * w.z + xv.w * w.w;
                }
                r[fi] = acc;
            }
            ushort4 o;
            o.x = f2bf(r[0]); o.y = f2bf(r[1]); o.z = f2bf(r[2]); o.w = f2bf(r[3]);
            tp[fg] = o;
        }
        return;
    }

    // ---------------- Binning path (R6-proven + degree histogram) ----------------
    if (tid < NBK) cnt[tid] = 0;
    __syncthreads();

    int base = blockIdx.x * 4096;
    int nedge = N_EDGES - base;
    if (nedge > 4096) nedge = 4096;

    int myb[16], myr[16], myp[16];
#pragma unroll
    for (int i = 0; i < 16; ++i) {
        int e = base + i * 256 + tid;
        myb[i] = -1;
        if (e < N_EDGES) {
            int s = src[e], d = dst[e];
            int b = d >> 8;
            myb[i] = b;
            myp[i] = ((d & 255) << 16) | s;
            myr[i] = atomicAdd(&cnt[b], 1);
            atomicAdd(&ncnt[d], 1);   // per-node degree (spread over 50K lines)
        }
    }
    __syncthreads();

    int c = (tid < NBK) ? cnt[tid] : 0;
    sb[tid] = c;
    __syncthreads();
    for (int off = 1; off < 256; off <<= 1) {
        int u = (tid >= off) ? sb[tid - off] : 0;
        __syncthreads();
        sb[tid] += u;
        __syncthreads();
    }
    if (tid < NBK) {
        lofs[tid] = sb[tid] - c;
        if (c) shiftv[tid] = tid * CSR_CAP + atomicAdd(&bcur[tid * 16], c) - lofs[tid];
    }
    __syncthreads();

#pragma unroll
    for (int i = 0; i < 16; ++i) {
        if (myb[i] >= 0) {
            int idx = lofs[myb[i]] + myr[i];
            stag[idx] = myp[i];
            stb[idx] = (unsigned char)myb[i];
        }
    }
    __syncthreads();

    for (int i = tid; i < nedge; i += 256)
        binned[i + shiftv[stb[i]]] = stag[i];
}

// One workgroup per (bucket, dst-quarter). Degrees precomputed in ncnt ->
// SINGLE filtered pass over binned (place only) + per-node pad-tail fill.
// Counts padded to mult-16 with dummy src = N_NODES. nodeinfo=(pcnt<<23)|pos.
__global__ __launch_bounds__(256) void build_csr(const int* __restrict__ binned,
                                                 const int* __restrict__ bcur,
                                                 const int* __restrict__ ncnt,
                                                 unsigned* __restrict__ nodeinfo,
                                                 unsigned short* __restrict__ csr16) {
    __shared__ int cnt2[64], ofs[64], sb[64];
    int tid = threadIdx.x;
    int b = blockIdx.x >> 2;
    int q = blockIdx.x & 3;
    int ibase = b * CSR_CAP;
    int qbase = (b * 4 + q) * QCAP;
    int m = bcur[b * 16];          // bucket edge count
    if (m > CSR_CAP) m = CSR_CAP;
    int node = (b << 8) + (q << 6) + tid;

    int v = 0, c0 = 0;
    if (tid < 64) {
        c0 = (node < N_NODES) ? ncnt[node] : 0;
        cnt2[tid] = 0;
        v = (c0 + 15) & ~15;       // mult-16 pad
        sb[tid] = v;
    }
    __syncthreads();
    for (int off = 1; off < 64; off <<= 1) {
        int u = (tid >= off && tid < 64) ? sb[tid - off] : 0;
        __syncthreads();
        if (tid < 64) sb[tid] += u;
        __syncthreads();
    }
    if (tid < 64) {
        ofs[tid] = sb[tid] - v;
        if (node < N_NODES)
            nodeinfo[node] = ((unsigned)v << 23) | (unsigned)(qbase + ofs[tid]);
        // pad tail fill: [c0, v) gets dummy row index
        int o = qbase + ofs[tid];
        for (int i = c0; i < v; ++i) csr16[o + i] = (unsigned short)N_NODES;
    }
    __syncthreads();

    // place pass (the only pass over binned)
    for (int i = tid; i < m; i += 256) {
        int p = binned[ibase + i];
        int dl = (p >> 16) & 255;
        if ((dl >> 6) == q) {
            int r = atomicAdd(&cnt2[dl & 63], 1);
            csr16[qbase + ofs[dl & 63] + r] = (unsigned short)(p & 0xFFFF);
        }
    }
}

// T(bf16) = X(bf16) @ W^T; dummy row zeroed. (layer 2)
__global__ __launch_bounds__(256) void gemm64_bf16(const unsigned short* __restrict__ X,
                                                   const float* __restrict__ W,
                                                   unsigned short* __restrict__ T,
                                                   int n_rows) {
    __shared__ float Ws[64 * 64];
    int tid = threadIdx.x;
#pragma unroll
    for (int j = 0; j < 16; ++j) Ws[j * 256 + tid] = W[j * 256 + tid];
    __syncthreads();

    int n = blockIdx.x * 256 + tid;
    if (n >= n_rows) {
        if (n == n_rows) {
            ushort4 z = {0, 0, 0, 0};
            ushort4* tp = (ushort4*)(T + (size_t)n * 64);
#pragma unroll
            for (int k = 0; k < 16; ++k) tp[k] = z;
        }
        return;
    }

    uint4 xr[8];  // 64 bf16 = 128 B
    const uint4* xp = (const uint4*)(X + (size_t)n * 64);
#pragma unroll
    for (int k = 0; k < 8; ++k) xr[k] = xp[k];
    float x[64];
    const unsigned* xu = (const unsigned*)xr;
#pragma unroll
    for (int p = 0; p < 32; ++p) {
        unsigned u = xu[p];
        x[2 * p] = bf_lo(u);
        x[2 * p + 1] = bf_hi(u);
    }

    const float4* xv4 = (const float4*)x;
    ushort4* tp = (ushort4*)(T + (size_t)n * 64);
    for (int fg = 0; fg < 16; ++fg) {
        float r[4];
#pragma unroll
        for (int fi = 0; fi < 4; ++fi) {
            int f = fg * 4 + fi;
            float acc = 0.f;
#pragma unroll
            for (int k4 = 0; k4 < 16; ++k4) {
                float4 w = *(const float4*)&Ws[f * 64 + k4 * 4];
                float4 xv = xv4[k4];
                acc += xv.x * w.x + xv.y * w.y + xv.z * w.z + xv.w * w.w;
            }
            r[fi] = acc;
        }
        ushort4 o;
        o.x = f2bf(r[0]); o.y = f2bf(r[1]); o.z = f2bf(r[2]); o.w = f2bf(r[3]);
        tp[fg] = o;
    }
}

// R11-proven aggregate: one 64-lane wave per node, lane = feature.
// Counts mult-16: 2 index uint4 loads + 16 independent 128B row gathers/iter.
__global__ __launch_bounds__(256) void aggregate(const unsigned short* __restrict__ T,
                                                 const unsigned short* __restrict__ csr,
                                                 const unsigned* __restrict__ nodeinfo,
                                                 const float* __restrict__ bias,
                                                 void* __restrict__ outp,
                                                 int mode) {
    int node = blockIdx.x * 4 + (threadIdx.x >> 6);
    int lane = threadIdx.x & 63;
    if (node >= N_NODES) return;
    unsigned info = nodeinfo[node];
    int pos = (int)(info & 0x7FFFFFu);
    int groups = (int)(info >> 23) >> 3;   // even (pcnt mult 16)
    const uint4* ix = (const uint4*)(csr + pos);  // 32B-aligned
    float acc = bias[lane];
    float acc2 = 0.f;
    for (int g = 0; g < groups; g += 2) {
        uint4 ia = ix[g];
        uint4 ib = ix[g + 1];
        int s0 = ia.x & 0xFFFF, s1 = ia.x >> 16;
        int s2 = ia.y & 0xFFFF, s3 = ia.y >> 16;
        int s4 = ia.z & 0xFFFF, s5 = ia.z >> 16;
        int s6 = ia.w & 0xFFFF, s7 = ia.w >> 16;
        int u0 = ib.x & 0xFFFF, u1 = ib.x >> 16;
        int u2 = ib.y & 0xFFFF, u3 = ib.y >> 16;
        int u4 = ib.z & 0xFFFF, u5 = ib.z >> 16;
        int u6 = ib.w & 0xFFFF, u7 = ib.w >> 16;
        unsigned short v0 = T[(size_t)s0 * DIM + lane];
        unsigned short v1 = T[(size_t)s1 * DIM + lane];
        unsigned short v2 = T[(size_t)s2 * DIM + lane];
        unsigned short v3 = T[(size_t)s3 * DIM + lane];
        unsigned short v4 = T[(size_t)s4 * DIM + lane];
        unsigned short v5 = T[(size_t)s5 * DIM + lane];
        unsigned short v6 = T[(size_t)s6 * DIM + lane];
        unsigned short v7 = T[(size_t)s7 * DIM + lane];
        unsigned short w0 = T[(size_t)u0 * DIM + lane];
        unsigned short w1 = T[(size_t)u1 * DIM + lane];
        unsigned short w2 = T[(size_t)u2 * DIM + lane];
        unsigned short w3 = T[(size_t)u3 * DIM + lane];
        unsigned short w4 = T[(size_t)u4 * DIM + lane];
        unsigned short w5 = T[(size_t)u5 * DIM + lane];
        unsigned short w6 = T[(size_t)u6 * DIM + lane];
        unsigned short w7 = T[(size_t)u7 * DIM + lane];
        acc  += (bf2f(v0) + bf2f(v1)) + (bf2f(v2) + bf2f(v3)) +
                (bf2f(v4) + bf2f(v5)) + (bf2f(v6) + bf2f(v7));
        acc2 += (bf2f(w0) + bf2f(w1)) + (bf2f(w2) + bf2f(w3)) +
                (bf2f(w4) + bf2f(w5)) + (bf2f(w6) + bf2f(w7));
    }
    acc += acc2;
    if (mode) {
        float e = __expf(2.f * acc);
        acc = 1.f - 2.f / (e + 1.f);
        ((unsigned short*)outp)[(size_t)node * DIM + lane] = f2bf(acc);
    } else {
        ((float*)outp)[(size_t)node * DIM + lane] = acc;
    }
}

extern "C" void kernel_launch(void* const* d_in, const int* in_sizes, int n_in,
                              void* d_out, int out_size, void* d_ws, size_t ws_size,
                              hipStream_t stream) {
    const float* feat = (const float*)d_in[0];
    const int*   src  = (const int*)d_in[1];
    const int*   dst  = (const int*)d_in[2];
    const float* W1   = (const float*)d_in[3];
    const float* b1   = (const float*)d_in[4];
    const float* W2   = (const float*)d_in[5];
    const float* b2   = (const float*)d_in[6];

    // ws layout (~21.5 MB)
    int*            binned   = (int*)d_ws;                                // 196*12288 ints
    unsigned short* csr16    = (unsigned short*)(binned + NBK * CSR_CAP); // 784*3072 ushort
    unsigned*       nodeinfo = (unsigned*)(csr16 + NBK * 4 * QCAP);       // 50000
    int*            bcur     = (int*)(nodeinfo + N_NODES);                // 196*16
    int*            ncnt     = bcur + NBK * 16;                           // 50000
    unsigned short* t        = (unsigned short*)(ncnt + N_NODES);         // 50001*64 bf16

    unsigned short* h = (unsigned short*)d_out;  // bf16 h staged in d_out
    float* out = (float*)d_out;

    // ---- CSR build + layer-1 transform (overlapped) ----
    hipMemsetAsync(bcur, 0, (NBK * 16 + N_NODES) * sizeof(int), stream);
    bin_and_gemm1<<<BIN_BLOCKS + GEMM_BLOCKS, 256, 0, stream>>>(
        src, dst, bcur, ncnt, binned, feat, W1, t);
    build_csr<<<NBK * 4, 256, 0, stream>>>(binned, bcur, ncnt, nodeinfo, csr16);

    // ---- Layer 1 aggregate: h = tanh(agg + b1), bf16 -> d_out ----
    aggregate<<<NB_AGG, 256, 0, stream>>>(t, csr16, nodeinfo, b1, h, 1);

    // ---- Layer 2: out = agg(h @ W2^T) + b2, f32 ----
    gemm64_bf16<<<GEMM_BLOCKS, 256, 0, stream>>>(h, W2, t, N_NODES);
    aggregate<<<NB_AGG, 256, 0, stream>>>(t, csr16, nodeinfo, b2, out, 0);
}

// Round 15
// 232.670 us; speedup vs baseline: 2.3114x; 1.2157x over previous
//
#include <hip/hip_runtime.h>

#define N_NODES 50000
#define N_EDGES 1600000
#define DIM 64
#define NBK 196          // buckets of 256 dst-nodes
#define BIN_BLOCKS 391   // ceil(1.6M / 4096)
#define CSR_CAP 12288    // per-bucket slots
#define QCAP 3072        // per-quarter slots (mult-16-padded mean ~2560, ~8-sigma margin)
#define GEMM_BLOCKS 197  // covers 50000 rows + dummy zero row
#define NB_AGG 12500     // aggregate blocks (4 nodes/block; 12500*4 == 50000 exactly)

// f32 -> bf16 round-to-nearest-even
__device__ __forceinline__ unsigned short f2bf(float f) {
    union { float f; unsigned u; } v; v.f = f;
    unsigned r = v.u + 0x7FFF + ((v.u >> 16) & 1);
    return (unsigned short)(r >> 16);
}
__device__ __forceinline__ float bf2f(unsigned short h) {
    union { unsigned u; float f; } v; v.u = ((unsigned)h) << 16;  return v.f;
}

// R11-verbatim fused kernel: blocks [0, BIN_BLOCKS) bin edges into per-bucket
// regions (bcur zero-based, memset first); blocks [BIN_BLOCKS, ..) T=feat@W1^T.
// NO ncnt histogram (R14: 1.6M global atomics cost ~50us). NO min-waves clause
// (R13: forcing 64 VGPR spilled the binning arrays -> 358us).
__global__ __launch_bounds__(256) void bin_and_gemm1(const int* __restrict__ src,
                                                     const int* __restrict__ dst,
                                                     int* __restrict__ bcur,
                                                     int* __restrict__ binned,
                                                     const float* __restrict__ X,
                                                     const float* __restrict__ W,
                                                     unsigned short* __restrict__ T) {
    __shared__ int cnt[NBK];
    __shared__ int lofs[NBK];
    __shared__ int shiftv[NBK];
    __shared__ int sb[256];
    __shared__ int stag[4096];
    __shared__ unsigned char stb[4096];
    __shared__ float Ws[64 * 64];
    int tid = threadIdx.x;

    if (blockIdx.x >= BIN_BLOCKS) {
        // ---------------- GEMM path (feat f32 -> T bf16) ----------------
#pragma unroll
        for (int j = 0; j < 16; ++j) Ws[j * 256 + tid] = W[j * 256 + tid];
        __syncthreads();

        int n = (blockIdx.x - BIN_BLOCKS) * 256 + tid;
        if (n > N_NODES) return;
        ushort4* tp = (ushort4*)(T + (size_t)n * 64);
        if (n == N_NODES) {  // dummy zero row (pad target for agg1)
            ushort4 z = {0, 0, 0, 0};
#pragma unroll
            for (int k = 0; k < 16; ++k) tp[k] = z;
            return;
        }

        float4 x[16];
        const float4* xp = (const float4*)(X + (size_t)n * 64);
#pragma unroll
        for (int k = 0; k < 16; ++k) x[k] = xp[k];

        for (int fg = 0; fg < 16; ++fg) {
            float r[4];
#pragma unroll
            for (int fi = 0; fi < 4; ++fi) {
                int f = fg * 4 + fi;
                float acc = 0.f;
#pragma unroll
                for (int k4 = 0; k4 < 16; ++k4) {
                    float4 w = *(const float4*)&Ws[f * 64 + k4 * 4];
                    float4 xv = x[k4];
                    acc += xv.x * w.x + xv.y * w.y + xv.z * w.z + xv.w * w.w;
                }
                r[fi] = acc;
            }
            ushort4 o;
            o.x = f2bf(r[0]); o.y = f2bf(r[1]); o.z = f2bf(r[2]); o.w = f2bf(r[3]);
            tp[fg] = o;
        }
        return;
    }

    // ---------------- Binning path (R6-proven) ----------------
    if (tid < NBK) cnt[tid] = 0;
    __syncthreads();

    int base = blockIdx.x * 4096;
    int nedge = N_EDGES - base;
    if (nedge > 4096) nedge = 4096;

    int myb[16], myr[16], myp[16];
#pragma unroll
    for (int i = 0; i < 16; ++i) {
        int e = base + i * 256 + tid;
        myb[i] = -1;
        if (e < N_EDGES) {
            int s = src[e], d = dst[e];
            int b = d >> 8;
            myb[i] = b;
            myp[i] = ((d & 255) << 16) | s;
            myr[i] = atomicAdd(&cnt[b], 1);
        }
    }
    __syncthreads();

    int c = (tid < NBK) ? cnt[tid] : 0;
    sb[tid] = c;
    __syncthreads();
    for (int off = 1; off < 256; off <<= 1) {
        int u = (tid >= off) ? sb[tid - off] : 0;
        __syncthreads();
        sb[tid] += u;
        __syncthreads();
    }
    if (tid < NBK) {
        lofs[tid] = sb[tid] - c;
        if (c) shiftv[tid] = tid * CSR_CAP + atomicAdd(&bcur[tid * 16], c) - lofs[tid];
    }
    __syncthreads();

#pragma unroll
    for (int i = 0; i < 16; ++i) {
        if (myb[i] >= 0) {
            int idx = lofs[myb[i]] + myr[i];
            stag[idx] = myp[i];
            stb[idx] = (unsigned char)myb[i];
        }
    }
    __syncthreads();

    for (int i = tid; i < nedge; i += 256)
        binned[i + shiftv[stb[i]]] = stag[i];
}

// R11-verbatim: one workgroup per (bucket, dst-quarter). Counts padded to
// mult-16 with dummy src = N_NODES (zero row). nodeinfo=(pcnt<<23)|pos, pos%16==0.
__global__ __launch_bounds__(256) void build_csr(const int* __restrict__ binned,
                                                 const int* __restrict__ bcur,
                                                 unsigned* __restrict__ nodeinfo,
                                                 unsigned short* __restrict__ csr16) {
    __shared__ int cnt[64], cnt2[64], ofs[64], sb[64];
    __shared__ int qtot;
    int tid = threadIdx.x;
    int b = blockIdx.x >> 2;
    int q = blockIdx.x & 3;
    int ibase = b * CSR_CAP;
    int qbase = (b * 4 + q) * QCAP;
    int m = bcur[b * 16];          // zero-based bucket edge count
    if (m > CSR_CAP) m = CSR_CAP;
    if (tid < 64) { cnt[tid] = 0; cnt2[tid] = 0; }
    __syncthreads();

    for (int i = tid; i < m; i += 256) {
        int dl = (binned[ibase + i] >> 16) & 255;
        if ((dl >> 6) == q) atomicAdd(&cnt[dl & 63], 1);
    }
    __syncthreads();

    int v = 0;
    if (tid < 64) { v = (cnt[tid] + 15) & ~15; sb[tid] = v; }  // mult-16 pad
    __syncthreads();
    for (int off = 1; off < 64; off <<= 1) {
        int u = (tid >= off && tid < 64) ? sb[tid - off] : 0;
        __syncthreads();
        if (tid < 64) sb[tid] += u;
        __syncthreads();
    }
    if (tid < 64) {
        ofs[tid] = sb[tid] - v;
        int node = (b << 8) + (q << 6) + tid;
        if (node < N_NODES)
            nodeinfo[node] = ((unsigned)v << 23) | (unsigned)(qbase + ofs[tid]);
    }
    if (tid == 63) qtot = sb[63];
    __syncthreads();

    int qt = qtot;
    for (int i = tid; i < qt; i += 256) csr16[qbase + i] = (unsigned short)N_NODES;
    __syncthreads();

    for (int i = tid; i < m; i += 256) {
        int p = binned[ibase + i];
        int dl = (p >> 16) & 255;
        if ((dl >> 6) == q) {
            int r = atomicAdd(&cnt2[dl & 63], 1);
            csr16[qbase + ofs[dl & 63] + r] = (unsigned short)(p & 0xFFFF);
        }
    }
}

// Layer-1 aggregate FUSED with the layer-2 transform:
//   h_row = tanh(gather-sum(T) + b1)  (f32, lane = feature, in-register)
//   t2_row = h_row @ W2^T             (LDS epilogue, no h round-trip, no gemm2)
// W2t4[k4*64+f] = W2[f][4k4..4k4+3] -> lane-striped float4 reads, conflict-free.
// Grid is exactly 50000 nodes (no early return -> barrier-uniform).
__global__ __launch_bounds__(256) void agg_fuse1(const unsigned short* __restrict__ T,
                                                 const unsigned short* __restrict__ csr,
                                                 const unsigned* __restrict__ nodeinfo,
                                                 const float* __restrict__ b1,
                                                 const float* __restrict__ W2,
                                                 unsigned short* __restrict__ T2) {
    __shared__ float4 W2t4[1024];   // 16 KB
    __shared__ float hsf[4 * 64];   // 1 KB, one h-row per wave
    int tid = threadIdx.x;
    int w = tid >> 6;
    int lane = tid & 63;
    int node = blockIdx.x * 4 + w;

    // stage W2 transposed (read before the single barrier below)
    for (int L4 = tid; L4 < 1024; L4 += 256) {
        int k4 = L4 >> 6, f = L4 & 63;
        W2t4[L4] = *(const float4*)(W2 + f * 64 + k4 * 4);
    }

    // ---- gather-accumulate (R11-proven core) ----
    unsigned info = nodeinfo[node];
    int pos = (int)(info & 0x7FFFFFu);
    int groups = (int)(info >> 23) >> 3;   // even (pcnt mult 16)
    const uint4* ix = (const uint4*)(csr + pos);
    float acc = b1[lane];
    float acc2 = 0.f;
    for (int g = 0; g < groups; g += 2) {
        uint4 ia = ix[g];
        uint4 ib = ix[g + 1];
        int s0 = ia.x & 0xFFFF, s1 = ia.x >> 16;
        int s2 = ia.y & 0xFFFF, s3 = ia.y >> 16;
        int s4 = ia.z & 0xFFFF, s5 = ia.z >> 16;
        int s6 = ia.w & 0xFFFF, s7 = ia.w >> 16;
        int u0 = ib.x & 0xFFFF, u1 = ib.x >> 16;
        int u2 = ib.y & 0xFFFF, u3 = ib.y >> 16;
        int u4 = ib.z & 0xFFFF, u5 = ib.z >> 16;
        int u6 = ib.w & 0xFFFF, u7 = ib.w >> 16;
        unsigned short v0 = T[(size_t)s0 * DIM + lane];
        unsigned short v1 = T[(size_t)s1 * DIM + lane];
        unsigned short v2 = T[(size_t)s2 * DIM + lane];
        unsigned short v3 = T[(size_t)s3 * DIM + lane];
        unsigned short v4 = T[(size_t)s4 * DIM + lane];
        unsigned short v5 = T[(size_t)s5 * DIM + lane];
        unsigned short v6 = T[(size_t)s6 * DIM + lane];
        unsigned short v7 = T[(size_t)s7 * DIM + lane];
        unsigned short w0 = T[(size_t)u0 * DIM + lane];
        unsigned short w1 = T[(size_t)u1 * DIM + lane];
        unsigned short w2 = T[(size_t)u2 * DIM + lane];
        unsigned short w3 = T[(size_t)u3 * DIM + lane];
        unsigned short w4 = T[(size_t)u4 * DIM + lane];
        unsigned short w5 = T[(size_t)u5 * DIM + lane];
        unsigned short w6 = T[(size_t)u6 * DIM + lane];
        unsigned short w7 = T[(size_t)u7 * DIM + lane];
        acc  += (bf2f(v0) + bf2f(v1)) + (bf2f(v2) + bf2f(v3)) +
                (bf2f(v4) + bf2f(v5)) + (bf2f(v6) + bf2f(v7));
        acc2 += (bf2f(w0) + bf2f(w1)) + (bf2f(w2) + bf2f(w3)) +
                (bf2f(w4) + bf2f(w5)) + (bf2f(w6) + bf2f(w7));
    }
    acc += acc2;

    // ---- tanh + in-block 64x64 GEMM epilogue ----
    float e = __expf(2.f * acc);
    hsf[w * 64 + lane] = 1.f - 2.f / (e + 1.f);
    __syncthreads();   // covers W2t4 staging + hs writes (all waves arrive)

    const float4* hv4 = (const float4*)&hsf[w * 64];
    float tf = 0.f;
#pragma unroll
    for (int k4 = 0; k4 < 16; ++k4) {
        float4 hv = hv4[k4];             // broadcast
        float4 wv = W2t4[k4 * 64 + lane];
        tf += hv.x * wv.x + hv.y * wv.y + hv.z * wv.z + hv.w * wv.w;
    }
    T2[(size_t)node * DIM + lane] = f2bf(tf);

    // zero T2's dummy pad row (block 0 only; agg2 gathers it for padding)
    if (blockIdx.x == 0 && tid < 64)
        T2[(size_t)N_NODES * DIM + tid] = 0;
}

// Layer-2 aggregate: out = gather-sum(T2) + b2, f32. (R11-proven core)
__global__ __launch_bounds__(256) void agg_out(const unsigned short* __restrict__ T,
                                               const unsigned short* __restrict__ csr,
                                               const unsigned* __restrict__ nodeinfo,
                                               const float* __restrict__ bias,
                                               float* __restrict__ outp) {
    int node = blockIdx.x * 4 + (threadIdx.x >> 6);
    int lane = threadIdx.x & 63;
    if (node >= N_NODES) return;
    unsigned info = nodeinfo[node];
    int pos = (int)(info & 0x7FFFFFu);
    int groups = (int)(info >> 23) >> 3;
    const uint4* ix = (const uint4*)(csr + pos);
    float acc = bias[lane];
    float acc2 = 0.f;
    for (int g = 0; g < groups; g += 2) {
        uint4 ia = ix[g];
        uint4 ib = ix[g + 1];
        int s0 = ia.x & 0xFFFF, s1 = ia.x >> 16;
        int s2 = ia.y & 0xFFFF, s3 = ia.y >> 16;
        int s4 = ia.z & 0xFFFF, s5 = ia.z >> 16;
        int s6 = ia.w & 0xFFFF, s7 = ia.w >> 16;
        int u0 = ib.x & 0xFFFF, u1 = ib.x >> 16;
        int u2 = ib.y & 0xFFFF, u3 = ib.y >> 16;
        int u4 = ib.z & 0xFFFF, u5 = ib.z >> 16;
        int u6 = ib.w & 0xFFFF, u7 = ib.w >> 16;
        unsigned short v0 = T[(size_t)s0 * DIM + lane];
        unsigned short v1 = T[(size_t)s1 * DIM + lane];
        unsigned short v2 = T[(size_t)s2 * DIM + lane];
        unsigned short v3 = T[(size_t)s3 * DIM + lane];
        unsigned short v4 = T[(size_t)s4 * DIM + lane];
        unsigned short v5 = T[(size_t)s5 * DIM + lane];
        unsigned short v6 = T[(size_t)s6 * DIM + lane];
        unsigned short v7 = T[(size_t)s7 * DIM + lane];
        unsigned short w0 = T[(size_t)u0 * DIM + lane];
        unsigned short w1 = T[(size_t)u1 * DIM + lane];
        unsigned short w2 = T[(size_t)u2 * DIM + lane];
        unsigned short w3 = T[(size_t)u3 * DIM + lane];
        unsigned short w4 = T[(size_t)u4 * DIM + lane];
        unsigned short w5 = T[(size_t)u5 * DIM + lane];
        unsigned short w6 = T[(size_t)u6 * DIM + lane];
        unsigned short w7 = T[(size_t)u7 * DIM + lane];
        acc  += (bf2f(v0) + bf2f(v1)) + (bf2f(v2) + bf2f(v3)) +
                (bf2f(v4) + bf2f(v5)) + (bf2f(v6) + bf2f(v7));
        acc2 += (bf2f(w0) + bf2f(w1)) + (bf2f(w2) + bf2f(w3)) +
                (bf2f(w4) + bf2f(w5)) + (bf2f(w6) + bf2f(w7));
    }
    acc += acc2;
    outp[(size_t)node * DIM + lane] = acc;
}

extern "C" void kernel_launch(void* const* d_in, const int* in_sizes, int n_in,
                              void* d_out, int out_size, void* d_ws, size_t ws_size,
                              hipStream_t stream) {
    const float* feat = (const float*)d_in[0];
    const int*   src  = (const int*)d_in[1];
    const int*   dst  = (const int*)d_in[2];
    const float* W1   = (const float*)d_in[3];
    const float* b1   = (const float*)d_in[4];
    const float* W2   = (const float*)d_in[5];
    const float* b2   = (const float*)d_in[6];
    float* out = (float*)d_out;

    // ws layout (~27.9 MB; harness poisons 256 MB of ws -> plenty)
    int*            binned   = (int*)d_ws;                                // 196*12288 ints
    unsigned short* csr16    = (unsigned short*)(binned + NBK * CSR_CAP); // 784*3072 ushort
    unsigned*       nodeinfo = (unsigned*)(csr16 + NBK * 4 * QCAP);       // 50000
    int*            bcur     = (int*)(nodeinfo + N_NODES);                // 196*16
    unsigned short* t        = (unsigned short*)(bcur + NBK * 16 + 8);    // 50001*64 bf16
    unsigned short* t2       = t + (size_t)(N_NODES + 1) * 64;            // 50001*64 bf16

    // ---- CSR build + layer-1 transform (overlapped) ----
    hipMemsetAsync(bcur, 0, NBK * 16 * sizeof(int), stream);
    bin_and_gemm1<<<BIN_BLOCKS + GEMM_BLOCKS, 256, 0, stream>>>(
        src, dst, bcur, binned, feat, W1, t);
    build_csr<<<NBK * 4, 256, 0, stream>>>(binned, bcur, nodeinfo, csr16);

    // ---- Layer 1 aggregate + fused layer-2 transform: t2 = tanh(agg+b1)@W2^T ----
    agg_fuse1<<<NB_AGG, 256, 0, stream>>>(t, csr16, nodeinfo, b1, W2, t2);

    // ---- Layer 2 aggregate: out = agg(t2) + b2, f32 ----
    agg_out<<<NB_AGG, 256, 0, stream>>>(t2, csr16, nodeinfo, b2, out);
}